// Round 10
// baseline (373.957 us; speedup 1.0000x reference)
//
#include <hip/hip_runtime.h>

typedef float f32x4 __attribute__((ext_vector_type(4)));
typedef short bf16x8 __attribute__((ext_vector_type(8)));
typedef unsigned short u16x8 __attribute__((ext_vector_type(8)));

__device__ __forceinline__ unsigned short f2bf(float f) {
  union { float f; unsigned int u; } c; c.f = f;
  unsigned int r = (c.u + 0x7fffu + ((c.u >> 16) & 1u)) >> 16;
  return (unsigned short)r;
}
__device__ __forceinline__ float bf2f(unsigned short u) {
  union { unsigned int u; float f; } c; c.u = ((unsigned int)u) << 16;
  return c.f;
}

// ---------------------------------------------------------------------------
// fp32 -> bf16 weight conversion, 5 segments (Wq,Wk,Wv,Wp,Wo), 512x512 each
// ---------------------------------------------------------------------------
struct CvtWArgs {
  const float* s[5];
  unsigned short* d[5];
};

__global__ __launch_bounds__(256) void cvt_w(CvtWArgs a) {
  const int seg = blockIdx.y;
  const float* __restrict__ src = a.s[seg];
  unsigned short* __restrict__ dst = a.d[seg];
  int i = (blockIdx.x * 256 + threadIdx.x) * 8;   // grid.x=128 -> exact
  float4 v0 = *(const float4*)&src[i];
  float4 v1 = *(const float4*)&src[i + 4];
  u16x8 o;
  o[0] = f2bf(v0.x); o[1] = f2bf(v0.y); o[2] = f2bf(v0.z); o[3] = f2bf(v0.w);
  o[4] = f2bf(v1.x); o[5] = f2bf(v1.y); o[6] = f2bf(v1.z); o[7] = f2bf(v1.w);
  *(u16x8*)&dst[i] = o;
}

// ---------------------------------------------------------------------------
// mask (int32, B*T*T) -> packed bits (1 = keep)
// ---------------------------------------------------------------------------
__global__ __launch_bounds__(256) void pack_mask(const int* __restrict__ mask,
                                                 unsigned long long* __restrict__ bits) {
  size_t i = (size_t)blockIdx.x * 256 + threadIdx.x;
  unsigned long long b = __ballot(mask[i] != 0);
  if ((threadIdx.x & 63) == 0) bits[i >> 6] = b;
}

// ---------------------------------------------------------------------------
// bf16 MFMA projection GEMM: out = X(M,512) @ W(512,512)^T (+bias)
// tile 128x64, 8 waves (4x2), wave tile 32x32, BK=64, XOR-swizzled LDS.
// 2-phase pipeline: issue loads for K-step k+1 before MFMA of step k (T14).
// MODE 0: out[((b*8+h)*1024+t)*64+d]; MODE 1: row-major; MODE 2: V^T layout.
// ---------------------------------------------------------------------------
template <int IN_FP32, typename OT, int MODE>
__global__ __launch_bounds__(512) void proj_mfma(
    const void* __restrict__ Xv, const unsigned short* __restrict__ W,
    const float* __restrict__ bias, OT* __restrict__ out)
{
  __shared__ unsigned short SM[128 * 64 + 64 * 64];   // AL | BL (contiguous)
  unsigned short* AL = SM;
  unsigned short* BL = SM + 128 * 64;
  const int tid = threadIdx.x;
  const int lane = tid & 63, wv = tid >> 6;
  const int lg = lane >> 4, lr = lane & 15;
  const int wm = wv >> 1, wn = wv & 1;                // 4 x 2 wave grid
  const int row0 = blockIdx.x * 128, col0 = blockIdx.y * 64;

  // staging thread map: A rows ar, ar+64 chunk au; B row ar chunk au
  const int au = tid & 7, ar = tid >> 3;

  f32x4 acc[2][2];
#pragma unroll
  for (int i = 0; i < 2; ++i)
#pragma unroll
    for (int j = 0; j < 2; ++j) { f32x4 z = {0.f,0.f,0.f,0.f}; acc[i][j] = z; }

  float4 a32[2][2];
  uint4 a16[2];
  uint4 breg;

  auto proj_issue = [&](int k0) {
    if constexpr (IN_FP32) {
      const float* X = (const float*)Xv;
#pragma unroll
      for (int j = 0; j < 2; ++j) {
        const float* p = &X[(size_t)(row0 + ar + 64 * j) * 512 + k0 + au * 8];
        a32[j][0] = *(const float4*)p;
        a32[j][1] = *(const float4*)(p + 4);
      }
    } else {
      const unsigned short* X = (const unsigned short*)Xv;
#pragma unroll
      for (int j = 0; j < 2; ++j)
        a16[j] = *(const uint4*)&X[(size_t)(row0 + ar + 64 * j) * 512 + k0 + au * 8];
    }
    breg = *(const uint4*)&W[(size_t)(col0 + ar) * 512 + k0 + au * 8];
  };
  auto proj_commit = [&]() {
    if constexpr (IN_FP32) {
#pragma unroll
      for (int j = 0; j < 2; ++j) {
        int r = ar + 64 * j;
        u16x8 o;
        o[0] = f2bf(a32[j][0].x); o[1] = f2bf(a32[j][0].y);
        o[2] = f2bf(a32[j][0].z); o[3] = f2bf(a32[j][0].w);
        o[4] = f2bf(a32[j][1].x); o[5] = f2bf(a32[j][1].y);
        o[6] = f2bf(a32[j][1].z); o[7] = f2bf(a32[j][1].w);
        *(u16x8*)&AL[r * 64 + ((au ^ (ar & 7)) << 3)] = o;
      }
    } else {
#pragma unroll
      for (int j = 0; j < 2; ++j) {
        int r = ar + 64 * j;
        *(uint4*)&AL[r * 64 + ((au ^ (ar & 7)) << 3)] = a16[j];
      }
    }
    *(uint4*)&BL[ar * 64 + ((au ^ (ar & 7)) << 3)] = breg;
  };

  proj_issue(0);
  proj_commit();

  for (int k0 = 0; k0 < 512; k0 += 64) {
    __syncthreads();                       // staged tile visible
    if (k0 < 448) proj_issue(k0 + 64);     // loads fly during compute

    bf16x8 af[2][2], bf[2][2];
#pragma unroll
    for (int mf = 0; mf < 2; ++mf)
#pragma unroll
      for (int ks = 0; ks < 2; ++ks) {
        int row = wm * 32 + mf * 16 + lr;
        af[mf][ks] = *(const bf16x8*)&AL[row * 64 + (((ks * 4 + lg) ^ (lr & 7)) << 3)];
      }
#pragma unroll
    for (int nf = 0; nf < 2; ++nf)
#pragma unroll
      for (int ks = 0; ks < 2; ++ks) {
        int col = wn * 32 + nf * 16 + lr;
        bf[nf][ks] = *(const bf16x8*)&BL[col * 64 + (((ks * 4 + lg) ^ (lr & 7)) << 3)];
      }
#pragma unroll
    for (int mf = 0; mf < 2; ++mf)
#pragma unroll
      for (int nf = 0; nf < 2; ++nf)
#pragma unroll
        for (int ks = 0; ks < 2; ++ks)
          acc[mf][nf] = __builtin_amdgcn_mfma_f32_16x16x32_bf16(
              af[mf][ks], bf[nf][ks], acc[mf][nf], 0, 0, 0);

    __syncthreads();                       // all reads done
    if (k0 < 448) proj_commit();           // write next tile
  }

  if constexpr (MODE == 2) {
    // ---- transpose epilogue via LDS (pad 73)
    unsigned short* TL = SM;                          // [128][73], 18688 B
    __syncthreads();
#pragma unroll
    for (int mf = 0; mf < 2; ++mf)
#pragma unroll
      for (int nf = 0; nf < 2; ++nf) {
        int dl = wn * 32 + nf * 16 + lr;
        float bv = bias[col0 + dl];
#pragma unroll
        for (int reg = 0; reg < 4; ++reg) {
          int tl = wm * 32 + mf * 16 + lg * 4 + reg;
          TL[tl * 73 + dl] = f2bf(acc[mf][nf][reg] + bv);
        }
      }
    __syncthreads();
    const int bI = row0 >> 10, hI = col0 >> 6, t0 = row0 & 1023;
#pragma unroll
    for (int j = 0; j < 2; ++j) {
      int slot = j * 512 + tid;        // 1024 slots: 64 d x 16 chunks
      int d = slot >> 4, ch = slot & 15;
      u16x8 o;
#pragma unroll
      for (int e = 0; e < 8; ++e) o[e] = TL[(ch * 8 + e) * 73 + d];
      *(u16x8*)&out[((size_t)((bI * 8 + hI) * 64) + d) * 1024 + t0 + ch * 8] = o;
    }
  } else {
#pragma unroll
    for (int mf = 0; mf < 2; ++mf)
#pragma unroll
      for (int nf = 0; nf < 2; ++nf) {
        int col = col0 + wn * 32 + nf * 16 + lr;
        float bv = (bias != nullptr) ? bias[col] : 0.f;
#pragma unroll
        for (int reg = 0; reg < 4; ++reg) {
          int n = row0 + wm * 32 + mf * 16 + lg * 4 + reg;
          float val = acc[mf][nf][reg] + bv;
          if (MODE == 0) {
            int bI = n >> 10, t = n & 1023, hI = col >> 6, d = col & 63;
            size_t off = ((size_t)(bI * 8 + hI) * 1024 + t) * 64 + d;
            if constexpr (sizeof(OT) == 2) out[off] = (OT)f2bf(val);
            else out[off] = (OT)val;
          } else {
            out[(size_t)n * 512 + col] = (OT)val;
          }
        }
      }
  }
}

// ---------------------------------------------------------------------------
// Fused flash attention, bf16 MFMA. Block: 64 q-rows of one (b,h); 4 waves
// x 16 rows. V pre-transposed (B,H,64,1024). 2-phase pipeline (T14):
// issue tile t+1 loads before computing tile t; write-back after barrier.
// PL round-trip is per-wave -> no block barrier between write and read.
// ---------------------------------------------------------------------------
__global__ __launch_bounds__(256) void attn_mfma(
    const unsigned short* __restrict__ Q, const unsigned short* __restrict__ K,
    const unsigned short* __restrict__ P, const unsigned short* __restrict__ Vt,
    const unsigned long long* __restrict__ bits,
    const float* __restrict__ ubias, const float* __restrict__ vbias,
    unsigned short* __restrict__ X)
{
  __shared__ unsigned short KL[64 * 128];   // K|P tile, swizzled
  __shared__ unsigned short VtL[64 * 64];   // V^T tile, swizzled
  __shared__ unsigned short PL[4 * 16 * 72]; // per-wave P staging (pad 72)

  const int tid = threadIdx.x;
  const int lane = tid & 63, wq = tid >> 6;
  const int lg = lane >> 4, lr = lane & 15;
  const int bh = blockIdx.y, b = bh >> 3, h = bh & 7;
  const int tw = blockIdx.x * 64 + wq * 16;

  // ---- Q' A-fragments: (q+u | q+v) * 0.125
  bf16x8 qa[4];
  {
    const unsigned short* qrow = Q + ((size_t)bh * 1024 + tw + lr) * 64;
    uint4 qlo = *(const uint4*)&qrow[lg * 8];
    uint4 qhi = *(const uint4*)&qrow[32 + lg * 8];
#pragma unroll
    for (int ks = 0; ks < 4; ++ks) {
      int d0 = (ks & 1) * 32 + lg * 8;
      const float* bb = (ks < 2) ? (ubias + h * 64) : (vbias + h * 64);
      float4 b0 = *(const float4*)&bb[d0];
      float4 b1 = *(const float4*)&bb[d0 + 4];
      uint4 qq = (ks & 1) ? qhi : qlo;
      unsigned int qw[4] = {qq.x, qq.y, qq.z, qq.w};
      float bbv[8] = {b0.x, b0.y, b0.z, b0.w, b1.x, b1.y, b1.z, b1.w};
      bf16x8 a;
#pragma unroll
      for (int e = 0; e < 8; ++e) {
        unsigned short qb = (e & 1) ? (unsigned short)(qw[e >> 1] >> 16)
                                    : (unsigned short)(qw[e >> 1] & 0xffffu);
        a[e] = (short)f2bf((bf2f(qb) + bbv[e]) * 0.125f);
      }
      qa[ks] = a;
    }
  }

  f32x4 Ofr[4];
  float m_[4], l_[4];
#pragma unroll
  for (int nf = 0; nf < 4; ++nf) { f32x4 z = {0.f,0.f,0.f,0.f}; Ofr[nf] = z; }
#pragma unroll
  for (int r = 0; r < 4; ++r) { m_[r] = -3.4e38f; l_[r] = 0.f; }

  const unsigned short* Kg = K + (size_t)bh * 65536;
  const unsigned short* Pg = P + (size_t)h * 65536;
  const unsigned short* Vg = Vt + (size_t)bh * 65536;   // (64 d, 1024 s)
  const unsigned long long* brow = bits + (size_t)b * 16384;
  unsigned short* Pl = PL + wq * (16 * 72);

  // staging thread map: K|P rows sr+16j chunk sc; Vt d-rows vd+32j chunk vu
  const int sc = tid & 15, sr = tid >> 4;
  const int vu = tid & 7, vd = tid >> 3;
  const unsigned short* kpsrc = (sc < 8) ? Kg : Pg;
  const int scc = sc & 7;
  uint4 kreg[4], vreg[2];

  auto attn_issue = [&](int s0) {
#pragma unroll
    for (int j = 0; j < 4; ++j)
      kreg[j] = *(const uint4*)&kpsrc[(size_t)(s0 + sr + 16 * j) * 64 + scc * 8];
#pragma unroll
    for (int j = 0; j < 2; ++j)
      vreg[j] = *(const uint4*)&Vg[(size_t)(vd + 32 * j) * 1024 + s0 + vu * 8];
  };
  auto attn_commit = [&]() {
#pragma unroll
    for (int j = 0; j < 4; ++j) {
      int r = sr + 16 * j;
      *(uint4*)&KL[r * 128 + ((sc ^ (sr & 7)) << 3)] = kreg[j];
    }
#pragma unroll
    for (int j = 0; j < 2; ++j) {
      int d = vd + 32 * j;
      *(uint4*)&VtL[d * 64 + ((vu ^ (vd & 7)) << 3)] = vreg[j];
    }
  };

  attn_issue(0);
  attn_commit();

  for (int s0t = 0; s0t < 16; ++s0t) {
    __syncthreads();                           // staged tile visible
    if (s0t < 15) attn_issue((s0t + 1) * 64);  // loads fly during compute

    // mask words (1 u64 per owned q-row for this 64-wide s tile)
    unsigned long long mw[4];
#pragma unroll
    for (int r = 0; r < 4; ++r)
      mw[r] = brow[(size_t)(tw + lg * 4 + r) * 16 + s0t];

    // QK^T (+relpos): S = Q' . (K|P)^T
    f32x4 S[4];
#pragma unroll
    for (int nf = 0; nf < 4; ++nf) {
      bf16x8 kb[4];
#pragma unroll
      for (int ks = 0; ks < 4; ++ks)
        kb[ks] = *(const bf16x8*)&KL[(nf * 16 + lr) * 128 + (((ks * 4 + lg) ^ (lr & 7)) << 3)];
      f32x4 a = {0.f, 0.f, 0.f, 0.f};
#pragma unroll
      for (int ks = 0; ks < 4; ++ks)
        a = __builtin_amdgcn_mfma_f32_16x16x32_bf16(qa[ks], kb[ks], a, 0, 0, 0);
      S[nf] = a;
    }

    // online softmax update (row stats via shfl within 16-lane groups)
#pragma unroll
    for (int r = 0; r < 4; ++r) {
      float v = fmaxf(fmaxf(S[0][r], S[1][r]), fmaxf(S[2][r], S[3][r]));
      v = fmaxf(v, __shfl_xor(v, 1));
      v = fmaxf(v, __shfl_xor(v, 2));
      v = fmaxf(v, __shfl_xor(v, 4));
      v = fmaxf(v, __shfl_xor(v, 8));
      float mo = m_[r];
      float mn = fmaxf(mo, v);
      m_[r] = mn;
      float sc2 = __expf(mo - mn);
      l_[r] *= sc2;
#pragma unroll
      for (int nf = 0; nf < 4; ++nf) Ofr[nf][r] *= sc2;
      float ps = 0.f;
#pragma unroll
      for (int nf = 0; nf < 4; ++nf) {
        float e = __expf(S[nf][r] - mn);
        e = ((mw[r] >> (nf * 16 + lr)) & 1ull) ? e : 0.f;
        S[nf][r] = e;
        ps += e;
      }
      ps += __shfl_xor(ps, 1);
      ps += __shfl_xor(ps, 2);
      ps += __shfl_xor(ps, 4);
      ps += __shfl_xor(ps, 8);
      l_[r] += ps;
    }

    // P -> per-wave LDS (bf16); same-wave readback needs only lgkmcnt,
    // which the compiler inserts (PL is private to this wave).
#pragma unroll
    for (int nf = 0; nf < 4; ++nf)
#pragma unroll
      for (int r = 0; r < 4; ++r)
        Pl[(lg * 4 + r) * 72 + nf * 16 + lr] = f2bf(S[nf][r]);

    bf16x8 pa[2];
#pragma unroll
    for (int k2 = 0; k2 < 2; ++k2)
      pa[k2] = *(const bf16x8*)&Pl[lr * 72 + k2 * 32 + lg * 8];
#pragma unroll
    for (int nf2 = 0; nf2 < 4; ++nf2) {
      int d = nf2 * 16 + lr;
      bf16x8 vb[2];
#pragma unroll
      for (int k2 = 0; k2 < 2; ++k2)
        vb[k2] = *(const bf16x8*)&VtL[d * 64 + (((k2 * 4 + lg) ^ (d & 7)) << 3)];
#pragma unroll
      for (int k2 = 0; k2 < 2; ++k2)
        Ofr[nf2] = __builtin_amdgcn_mfma_f32_16x16x32_bf16(
            pa[k2], vb[k2], Ofr[nf2], 0, 0, 0);
    }

    __syncthreads();                           // all LDS reads done
    if (s0t < 15) attn_commit();               // write next tile
  }

  // epilogue: O / l  (l==0 -> 0), write bf16 (B,T,512)
#pragma unroll
  for (int r = 0; r < 4; ++r) {
    float l = l_[r];
    float inv = (l > 0.f) ? 1.f / l : 0.f;
    int t = tw + lg * 4 + r;
#pragma unroll
    for (int nf2 = 0; nf2 < 4; ++nf2)
      X[((size_t)b * 1024 + t) * 512 + h * 64 + nf2 * 16 + lr] =
          f2bf(Ofr[nf2][r] * inv);
  }
}

extern "C" void kernel_launch(void* const* d_in, const int* in_sizes, int n_in,
                              void* d_out, int out_size, void* d_ws, size_t ws_size,
                              hipStream_t stream) {
  const float* query = (const float*)d_in[0];
  const float* key   = (const float*)d_in[1];
  const float* value = (const float*)d_in[2];
  const int*   mask  = (const int*)d_in[3];
  const float* pos   = (const float*)d_in[4];
  const float* Wq = (const float*)d_in[5];
  const float* bq = (const float*)d_in[6];
  const float* Wk = (const float*)d_in[7];
  const float* bk = (const float*)d_in[8];
  const float* Wv = (const float*)d_in[9];
  const float* bv = (const float*)d_in[10];
  const float* Wp = (const float*)d_in[11];
  const float* Wo = (const float*)d_in[12];
  const float* bo = (const float*)d_in[13];
  const float* ub = (const float*)d_in[14];
  const float* vb = (const float*)d_in[15];
  float* out = (float*)d_out;

  char* w = (char*)d_ws;
  auto alloc = [&](size_t bytes) {
    char* p = w; w += (bytes + 255) & ~(size_t)255; return p;
  };
  const size_t NA = (size_t)8 * 1024 * 512;      // activation elems (B,T,F)
  const size_t NW = (size_t)512 * 512;           // weight elems
  const size_t NP = (size_t)1024 * 512;          // pos elems

  // total ws usage ~= 36.5 MB (validated fits in round 5)
  unsigned short* wsQ  = (unsigned short*)alloc(NA * 2);       // (B,H,T,D) bf16
  unsigned short* wsK  = (unsigned short*)alloc(NA * 2);
  unsigned short* wsVt = (unsigned short*)alloc(NA * 2);       // (B,H,64,1024) bf16
  unsigned short* wsP  = (unsigned short*)alloc(NP * 2);       // (H,T,D) bf16
  unsigned short* wsX  = (unsigned short*)alloc(NA * 2);       // (B,T,512) bf16
  unsigned long long* bitsW = (unsigned long long*)alloc((size_t)8 * 1024 * 16 * 8);
  unsigned short* Wqb = (unsigned short*)alloc(NW * 2);
  unsigned short* Wkb = (unsigned short*)alloc(NW * 2);
  unsigned short* Wvb = (unsigned short*)alloc(NW * 2);
  unsigned short* Wpb = (unsigned short*)alloc(NW * 2);
  unsigned short* Wob = (unsigned short*)alloc(NW * 2);

  CvtWArgs ca;
  ca.s[0] = Wq; ca.d[0] = Wqb;
  ca.s[1] = Wk; ca.d[1] = Wkb;
  ca.s[2] = Wv; ca.d[2] = Wvb;
  ca.s[3] = Wp; ca.d[3] = Wpb;
  ca.s[4] = Wo; ca.d[4] = Wob;

  cvt_w<<<dim3(128, 5), dim3(256), 0, stream>>>(ca);
  pack_mask<<<dim3(32768), dim3(256), 0, stream>>>(mask, bitsW);
  proj_mfma<1, unsigned short, 0><<<dim3(64, 8), dim3(512), 0, stream>>>(query, Wqb, bq, wsQ);
  proj_mfma<1, unsigned short, 0><<<dim3(64, 8), dim3(512), 0, stream>>>(key,   Wkb, bk, wsK);
  proj_mfma<1, unsigned short, 2><<<dim3(64, 8), dim3(512), 0, stream>>>(value, Wvb, bv, wsVt);
  proj_mfma<1, unsigned short, 0><<<dim3(8, 8),  dim3(512), 0, stream>>>(pos,   Wpb, nullptr, wsP);
  attn_mfma<<<dim3(16, 64), dim3(256), 0, stream>>>(wsQ, wsK, wsP, wsVt, bitsW, ub, vb, wsX);
  proj_mfma<0, float, 1><<<dim3(64, 8), dim3(512), 0, stream>>>(wsX, Wob, bo, out);
}